// Round 3
// baseline (22270.743 us; speedup 1.0000x reference)
//
#include <hip/hip_runtime.h>
#include <cstdint>
#include <math.h>

#define B_ 512
#define S_ 100
#define E_ 256
#define H_ 256

__device__ __forceinline__ float sigmoidf_(float x){ return 1.0f/(1.0f+expf(-x)); }

// Threefry-2x32, 20 rounds — matches jax/_src/prng.py lowering exactly.
__device__ __forceinline__ void threefry2x32_(uint32_t k0, uint32_t k1,
                                              uint32_t c0, uint32_t c1,
                                              uint32_t& o0, uint32_t& o1){
  uint32_t ks2 = k0 ^ k1 ^ 0x1BD11BDAu;
  uint32_t x0 = c0 + k0, x1 = c1 + k1;
#define ROT_(x,d) (((x)<<(d))|((x)>>(32-(d))))
#define RND_(r) { x0 += x1; x1 = ROT_(x1,(r)); x1 ^= x0; }
  RND_(13) RND_(15) RND_(26) RND_(6)  x0 += k1;  x1 += ks2 + 1u;
  RND_(17) RND_(29) RND_(16) RND_(24) x0 += ks2; x1 += k0  + 2u;
  RND_(13) RND_(15) RND_(26) RND_(6)  x0 += k0;  x1 += k1  + 3u;
  RND_(17) RND_(29) RND_(16) RND_(24) x0 += k1;  x1 += ks2 + 4u;
  RND_(13) RND_(15) RND_(26) RND_(6)  x0 += ks2; x1 += k0  + 5u;
#undef RND_
#undef ROT_
  o0 = x0; o1 = x1;
}

__device__ __forceinline__ float gumbel_bits_(uint32_t bits){
  const float tiny = 1.175494350822287508e-38f;
  float u = __uint_as_float((bits >> 9) | 0x3f800000u) - 1.0f; // [0,1)
  u = fmaxf(tiny, u + tiny);
  return -logf(-logf(u));
}

__device__ __forceinline__ float wsum_(float v){
  #pragma unroll
  for (int d = 32; d > 0; d >>= 1) v += __shfl_xor(v, d, 64);
  return v;
}
__device__ __forceinline__ float wmax_(float v){
  #pragma unroll
  for (int d = 32; d > 0; d >>= 1) v = fmaxf(v, __shfl_xor(v, d, 64));
  return v;
}

// ---------- prep kernels ----------
// W4[k][u][g] = (k<256 ? Wih[g*256+u][k] : Whh[g*256+u][k-256])
__global__ __launch_bounds__(256) void prep_w4(const float* __restrict__ Wih,
                                               const float* __restrict__ Whh,
                                               float* __restrict__ W4){
  int idx = blockIdx.x*256 + threadIdx.x;            // 512*256*4
  int g = idx & 3, u = (idx >> 2) & 255, k = idx >> 10;
  int row = g*256 + u;
  W4[idx] = (k < 256) ? Wih[row*256 + k] : Whh[row*256 + (k-256)];
}
// b4[u][g] = bih[g*256+u] + bhh[g*256+u]
__global__ __launch_bounds__(256) void prep_b4(const float* __restrict__ b1,
                                               const float* __restrict__ b2,
                                               float* __restrict__ o){
  int idx = blockIdx.x*256 + threadIdx.x;            // 1024
  if (idx < 1024) {
    int g = idx & 3, u = idx >> 2;
    o[idx] = b1[g*256 + u] + b2[g*256 + u];
  }
}
// dst[k][u] = src[u][k]  (256x256)
__global__ __launch_bounds__(256) void transpose256(const float* __restrict__ src,
                                                    float* __restrict__ dst){
  int idx = blockIdx.x*256 + threadIdx.x;            // 65536
  int r = idx >> 8, cc = idx & 255;
  dst[idx] = src[cc*256 + r];
}
__global__ __launch_bounds__(256) void init_state(float* __restrict__ h, float* __restrict__ c,
                                                  int* __restrict__ mask, int* __restrict__ sel){
  int i = blockIdx.x*256 + threadIdx.x;              // 512 blocks
  if (i < B_*H_) { h[i] = 0.f; c[i] = 0.f; }
  if (i < B_*S_) mask[i] = 0;
  if (i < B_)    sel[i]  = -1;
}

// ---------- fused LSTM step v2 ----------
// 256 blocks: 8 batch rows x 64 units each. thread = (unit uu, row-group rg);
// owns 2 rows x unit x 4 gates. One float4 weight load per k.
// h is ping-pong buffered (hr read / hw write) because unit-split blocks share rows.
__global__ __launch_bounds__(256) void lstm_step2(
    const float* __restrict__ W4,     // [512][256][4]
    const float* __restrict__ b4,     // [256][4]
    const float* __restrict__ coords, // [B,2,S]
    const float* __restrict__ emb,    // [2,256]
    const float* __restrict__ start,  // [256] or null
    const int*   __restrict__ sel,    // [B] or null
    const float* __restrict__ hr,
    float* __restrict__ hw,
    float* __restrict__ cst,          // c in-place (owner-only)
    float* __restrict__ enc_out,      // [B,S,H] or null
    int t, int mode)
{
  const int tid = threadIdx.x;
  const int uu  = tid & 63;
  const int rg  = tid >> 6;
  const int b0  = (blockIdx.x >> 2) * 8;
  const int u0  = (blockIdx.x & 3) * 64;
  __shared__ float Xs[512*8];   // [k][row]

  for (int i = tid; i < 4096; i += 256) {
    const int k = i >> 3, r = i & 7, b = b0 + r;
    float v;
    if (k < 256) {
      if (mode == 0) {
        v = coords[b*200 + t]*emb[k] + coords[b*200 + 100 + t]*emb[256 + k];
      } else {
        const int s = sel[b];
        if (s < 0) v = start[k];
        else       v = coords[b*200 + s]*emb[k] + coords[b*200 + 100 + s]*emb[256 + k];
      }
    } else {
      v = hr[b*256 + (k - 256)];
    }
    Xs[i] = v;
  }
  __syncthreads();

  float a0x=0.f,a0y=0.f,a0z=0.f,a0w=0.f, a1x=0.f,a1y=0.f,a1z=0.f,a1w=0.f;
  const float* wp = W4 + (size_t)(u0 + uu)*4;
  #pragma unroll 4
  for (int k = 0; k < 512; ++k) {
    const float4 w = *(const float4*)(wp + (size_t)k*1024);
    const float2 x = *(const float2*)(Xs + k*8 + rg*2);
    a0x += x.x*w.x; a0y += x.x*w.y; a0z += x.x*w.z; a0w += x.x*w.w;
    a1x += x.y*w.x; a1y += x.y*w.y; a1z += x.y*w.z; a1w += x.y*w.w;
  }

  const float4 bb = *(const float4*)(b4 + (u0 + uu)*4);
  const int u = u0 + uu;
  {
    const int b = b0 + rg*2;
    const float gi = a0x + bb.x, gf = a0y + bb.y, gg = a0z + bb.z, go = a0w + bb.w;
    const float cN = sigmoidf_(gf)*cst[b*256+u] + sigmoidf_(gi)*tanhf(gg);
    const float hN = sigmoidf_(go)*tanhf(cN);
    cst[b*256+u] = cN; hw[b*256+u] = hN;
    if (mode == 0) enc_out[((size_t)b*S_ + t)*H_ + u] = hN;
  }
  {
    const int b = b0 + rg*2 + 1;
    const float gi = a1x + bb.x, gf = a1y + bb.y, gg = a1z + bb.z, go = a1w + bb.w;
    const float cN = sigmoidf_(gf)*cst[b*256+u] + sigmoidf_(gi)*tanhf(gg);
    const float hN = sigmoidf_(go)*tanhf(cN);
    cst[b*256+u] = cN; hw[b*256+u] = hN;
    if (mode == 0) enc_out[((size_t)b*S_ + t)*H_ + u] = hN;
  }
}

// ---------- batched matvec: out[b][n] = bias[n] + X[b]@WT[:,n], 4 rows/block ----------
__global__ __launch_bounds__(256) void matvec_bias(
    const float* __restrict__ X, const float* __restrict__ WT,
    const float* __restrict__ bias, float* __restrict__ out)
{
  const int tid = threadIdx.x;
  const int b0 = blockIdx.x * 4;
  __shared__ float Xs[1024];    // [k][row]
  for (int i = tid; i < 1024; i += 256)
    Xs[i] = X[(b0 + (i & 3))*256 + (i >> 2)];
  __syncthreads();
  float a0 = bias[tid];
  float a1 = a0, a2 = a0, a3 = a0;
  #pragma unroll 4
  for (int k = 0; k < 256; ++k) {
    const float w = WT[k*256 + tid];
    const float4 x = *(const float4*)(Xs + k*4);
    a0 += x.x*w; a1 += x.y*w; a2 += x.z*w; a3 += x.w*w;
  }
  out[(b0+0)*256 + tid] = a0;
  out[(b0+1)*256 + tid] = a1;
  out[(b0+2)*256 + tid] = a2;
  out[(b0+3)*256 + tid] = a3;
}

// ---------- glimpse: logits -> softmax -> q ----------
__global__ __launch_bounds__(256) void glimpse_step(
    const float* __restrict__ qqIn, const float* __restrict__ enc,
    const float* __restrict__ ref_g, const float* __restrict__ g_V,
    const int* __restrict__ mask, float* __restrict__ qOut)
{
  const int b = blockIdx.x, tid = threadIdx.x, lane = tid & 63, wv = tid >> 6;
  __shared__ float qqs[256], gVs[256], lg[128], alpha[128];
  qqs[tid] = qqIn[b*256 + tid];
  gVs[tid] = g_V[tid];
  __syncthreads();

  const float* rg = ref_g + (size_t)b*S_*H_;
  const int* mk = mask + b*S_;
  for (int is = 0; is < 25; ++is) {
    const int s = is*4 + wv;
    float p = 0.f;
    #pragma unroll
    for (int j = 0; j < 4; ++j) {
      const int hh = lane + 64*j;
      p += gVs[hh] * tanhf(qqs[hh] + rg[s*256 + hh]);
    }
    p = wsum_(p);
    if (lane == 0) lg[s] = mk[s] ? -INFINITY : p;
  }
  __syncthreads();

  if (wv == 0) {
    const float v0 = lg[lane];
    const float v1 = (lane + 64 < S_) ? lg[lane + 64] : -INFINITY;
    const float m  = wmax_(fmaxf(v0, v1));
    const float e0 = expf(v0 - m);
    const float e1 = (lane + 64 < S_) ? expf(v1 - m) : 0.f;
    const float sm = wsum_(e0 + e1);
    alpha[lane] = e0 / sm;
    if (lane + 64 < S_) alpha[lane + 64] = e1 / sm;
  }
  __syncthreads();

  const float* eb = enc + (size_t)b*S_*H_;
  float a = 0.f;
  for (int s = 0; s < S_; ++s) a += alpha[s] * eb[s*256 + tid];
  qOut[b*256 + tid] = a;
}

// ---------- pointer: logits -> probs -> sample -> mask/sel ----------
__global__ __launch_bounds__(256) void pointer_step(
    const float* __restrict__ pqIn, const float* __restrict__ ref_p,
    const float* __restrict__ p_V,
    int* __restrict__ mask, int* __restrict__ sel,
    float* __restrict__ probs_out, float* __restrict__ idx_out, int t)
{
  const int b = blockIdx.x, tid = threadIdx.x, lane = tid & 63, wv = tid >> 6;
  __shared__ float pqs[256], pVs[256], lp[128];
  pqs[tid] = pqIn[b*256 + tid];
  pVs[tid] = p_V[tid];
  __syncthreads();

  const float* rp = ref_p + (size_t)b*S_*H_;
  const int* mk = mask + b*S_;
  for (int is = 0; is < 25; ++is) {
    const int s = is*4 + wv;
    float p = 0.f;
    #pragma unroll
    for (int j = 0; j < 4; ++j) {
      const int hh = lane + 64*j;
      p += pVs[hh] * tanhf(pqs[hh] + rp[s*256 + hh]);
    }
    p = wsum_(p);
    if (lane == 0) {
      const float v = 10.0f * tanhf(p);
      lp[s] = mk[s] ? -INFINITY : v;
    }
  }
  __syncthreads();

  if (wv == 0) {
    const float v0 = lp[lane];
    const float v1 = (lane + 64 < S_) ? lp[lane + 64] : -INFINITY;
    const float m  = wmax_(fmaxf(v0, v1));
    const float e0 = expf(v0 - m);
    const float e1 = (lane + 64 < S_) ? expf(v1 - m) : 0.f;
    const float sm = wsum_(e0 + e1);
    float* po = probs_out + ((size_t)t*B_ + b)*S_;
    po[lane] = e0 / sm;
    if (lane + 64 < S_) po[lane + 64] = e1 / sm;

    uint32_t k0, k1; threefry2x32_(0u, 1u, 0u, (uint32_t)t, k0, k1);
    uint32_t r0, r1;
    threefry2x32_(k0, k1, 0u, (uint32_t)(b*S_ + lane), r0, r1);
    float z0 = v0 + gumbel_bits_(r0 ^ r1);
    float z1 = -INFINITY;
    if (lane + 64 < S_) {
      uint32_t q0, q1;
      threefry2x32_(k0, k1, 0u, (uint32_t)(b*S_ + lane + 64), q0, q1);
      z1 = v1 + gumbel_bits_(q0 ^ q1);
    }
    float bv; int bi;
    if (z1 > z0) { bv = z1; bi = lane + 64; } else { bv = z0; bi = lane; }
    #pragma unroll
    for (int d = 32; d > 0; d >>= 1) {
      const float ov = __shfl_xor(bv, d, 64);
      const int   oi = __shfl_xor(bi, d, 64);
      if (ov > bv || (ov == bv && oi < bi)) { bv = ov; bi = oi; }
    }
    if (lane == 0) {
      idx_out[t*B_ + b] = (float)bi;
      sel[b] = bi;
      mask[b*S_ + bi] = 1;
    }
  }
}

// ---------- ref_g / ref_p projection GEMM ----------
__global__ __launch_bounds__(256) void gemm_ref(
    const float* __restrict__ A, const float* __restrict__ Bt,
    const float* __restrict__ bias, float* __restrict__ C)
{
  const int tid = threadIdx.x;
  const int m0 = blockIdx.x * 128, n0 = blockIdx.y * 128;
  __shared__ float As[8][128];
  __shared__ float Bs[8][128];
  float acc[8][8] = {};
  const int tx = tid & 15, ty = tid >> 4;

  for (int k0 = 0; k0 < 256; k0 += 8) {
    {
      const int row = tid >> 1, q = tid & 1;
      const float4 av = *(const float4*)(A + (size_t)(m0+row)*256 + k0 + q*4);
      As[q*4+0][row] = av.x; As[q*4+1][row] = av.y;
      As[q*4+2][row] = av.z; As[q*4+3][row] = av.w;
    }
    {
      const int kk = tid >> 5, nq = tid & 31;
      *(float4*)(&Bs[kk][nq*4]) = *(const float4*)(Bt + (size_t)(k0+kk)*256 + n0 + nq*4);
    }
    __syncthreads();
    #pragma unroll
    for (int k = 0; k < 8; ++k) {
      float a[8], bb[8];
      *(float4*)&a[0]  = *(const float4*)&As[k][ty*8];
      *(float4*)&a[4]  = *(const float4*)&As[k][ty*8+4];
      *(float4*)&bb[0] = *(const float4*)&Bs[k][tx*8];
      *(float4*)&bb[4] = *(const float4*)&Bs[k][tx*8+4];
      #pragma unroll
      for (int i = 0; i < 8; ++i)
        #pragma unroll
        for (int j = 0; j < 8; ++j)
          acc[i][j] += a[i]*bb[j];
    }
    __syncthreads();
  }
  #pragma unroll
  for (int i = 0; i < 8; ++i) {
    const int m = m0 + ty*8 + i;
    #pragma unroll
    for (int j = 0; j < 8; j += 4) {
      const int n = n0 + tx*8 + j;
      float4 o;
      o.x = acc[i][j  ] + bias[n  ];
      o.y = acc[i][j+1] + bias[n+1];
      o.z = acc[i][j+2] + bias[n+2];
      o.w = acc[i][j+3] + bias[n+3];
      *(float4*)(C + (size_t)m*256 + n) = o;
    }
  }
}

extern "C" void kernel_launch(void* const* d_in, const int* in_sizes, int n_in,
                              void* d_out, int out_size, void* d_ws, size_t ws_size,
                              hipStream_t stream) {
  (void)in_sizes; (void)n_in; (void)out_size; (void)ws_size;
  const float* inputs = (const float*)d_in[0];
  const float* emb    = (const float*)d_in[1];
  const float* eWih   = (const float*)d_in[2];
  const float* eWhh   = (const float*)d_in[3];
  const float* ebih   = (const float*)d_in[4];
  const float* ebhh   = (const float*)d_in[5];
  const float* dWih   = (const float*)d_in[6];
  const float* dWhh   = (const float*)d_in[7];
  const float* dbih   = (const float*)d_in[8];
  const float* dbhh   = (const float*)d_in[9];
  const float* gWq    = (const float*)d_in[10];
  const float* gbq    = (const float*)d_in[11];
  const float* gWr    = (const float*)d_in[12];
  const float* gbr    = (const float*)d_in[13];
  const float* gV     = (const float*)d_in[14];
  const float* pWq    = (const float*)d_in[15];
  const float* pbq    = (const float*)d_in[16];
  const float* pWr    = (const float*)d_in[17];
  const float* pbr    = (const float*)d_in[18];
  const float* pV     = (const float*)d_in[19];
  const float* start  = (const float*)d_in[20];

  float* ws = (float*)d_ws;
  size_t o = 0;
  float* W4E  = ws + o; o += (size_t)512*1024;
  float* W4D  = ws + o; o += (size_t)512*1024;
  float* b4E  = ws + o; o += 1024;
  float* b4D  = ws + o; o += 1024;
  float* gWqT = ws + o; o += 65536;
  float* pWqT = ws + o; o += 65536;
  float* gWrT = ws + o; o += 65536;
  float* pWrT = ws + o; o += 65536;
  float* enc  = ws + o; o += (size_t)B_*S_*H_;
  float* refg = ws + o; o += (size_t)B_*S_*H_;
  float* refp = ws + o; o += (size_t)B_*S_*H_;
  float* h0   = ws + o; o += (size_t)B_*H_;
  float* h1   = ws + o; o += (size_t)B_*H_;
  float* c    = ws + o; o += (size_t)B_*H_;
  float* qq   = ws + o; o += (size_t)B_*H_;
  float* qb   = ws + o; o += (size_t)B_*H_;
  float* pq   = ws + o; o += (size_t)B_*H_;
  int* mask   = (int*)(ws + o); o += (size_t)B_*S_;
  int* sel    = (int*)(ws + o); o += B_;

  float* probs = (float*)d_out;
  float* idxo  = probs + (size_t)S_*B_*S_;

  float* hpp[2] = {h0, h1};
  int p = 0;

  prep_w4<<<2048,256,0,stream>>>(eWih, eWhh, W4E);
  prep_w4<<<2048,256,0,stream>>>(dWih, dWhh, W4D);
  prep_b4<<<4,256,0,stream>>>(ebih, ebhh, b4E);
  prep_b4<<<4,256,0,stream>>>(dbih, dbhh, b4D);
  transpose256<<<256,256,0,stream>>>(gWq, gWqT);
  transpose256<<<256,256,0,stream>>>(pWq, pWqT);
  transpose256<<<256,256,0,stream>>>(gWr, gWrT);
  transpose256<<<256,256,0,stream>>>(pWr, pWrT);
  init_state<<<512,256,0,stream>>>(h0, c, mask, sel);

  for (int t = 0; t < S_; ++t) {
    lstm_step2<<<256,256,0,stream>>>(W4E, b4E, inputs, emb, nullptr, nullptr,
                                     hpp[p], hpp[1-p], c, enc, t, 0);
    p ^= 1;
  }

  gemm_ref<<<dim3(400,2),256,0,stream>>>(enc, gWrT, gbr, refg);
  gemm_ref<<<dim3(400,2),256,0,stream>>>(enc, pWrT, pbr, refp);

  for (int t = 0; t < S_; ++t) {
    lstm_step2<<<256,256,0,stream>>>(W4D, b4D, inputs, emb, start, sel,
                                     hpp[p], hpp[1-p], c, nullptr, t, 1);
    p ^= 1;
    matvec_bias<<<128,256,0,stream>>>(hpp[p], gWqT, gbq, qq);
    glimpse_step<<<512,256,0,stream>>>(qq, enc, refg, gV, mask, qb);
    matvec_bias<<<128,256,0,stream>>>(qb, pWqT, pbq, pq);
    pointer_step<<<512,256,0,stream>>>(pq, refp, pV, mask, sel, probs, idxo, t);
  }
}